// Round 1
// baseline (2107.862 us; speedup 1.0000x reference)
//
#include <hip/hip_runtime.h>

// ============================================================================
// CrossNeuronBlock — fp32 baseline, full pipeline on device.
//
// Shapes: x (16,1024,48,48). 4 exact 24x24 tiles -> B=64 chunk-batches,
// S=576, C=1024, H=72, 2 channel blocks of 512.
//
// Layout choice: activations stored (B, C, S) = rows m=(b*1024+c), 576 cols.
//  - extraction is a pure gather, coalesced both sides
//  - MLP GEMMs are NT (both operands K-contiguous)
//  - attn stored transposed At[d][c] -> softmax along contiguous axis, and
//    bmm becomes NN GEMM At(512x512) @ xv1_blk(512x576) -> (B,C,S) directly
//  - BN stats are column sums of a (65536 x 576) row-major matrix
//
// ws layout (bytes):
//   xv0   @ 0           37,748,736 fl   (reused as out2)
//   xv1   @ 150994944   37,748,736 fl   (reused as out3)
//   Hbuf  @ 301989888    4,718,592 fl
//   At    @ 320864256   33,554,432 fl
//   xm    @ 455081984       65,536 fl
//   stats @ 455344128        1,152 fl
// total ~455.4 MB
// ============================================================================

#define EPS 1e-5f

// ---- gather x -> xv0[(b*1024+c)*576 + s] ------------------------------------
__global__ void extract_k(const float* __restrict__ x, float* __restrict__ xv)
{
    int i = blockIdx.x * 256 + threadIdx.x;          // 0 .. 37,748,735
    int s = i % 576;
    int m = i / 576;
    int c = m & 1023;
    int b = m >> 10;
    int n = b & 15, ti = b >> 4;
    int ty = (ti >> 1) * 24, tx = (ti & 1) * 24;
    int sy = s / 24, sx = s - sy * 24;
    xv[i] = x[(((n << 10) + c) * 48 + ty + sy) * 48 + tx + sx];
}

// ---- generic tiled NT GEMM: C[m,n] = sum_k A[m,k]*B[n,k] (+bias[n]) (relu) --
template<int DO_RELU, int HAS_BIAS>
__global__ void gemm_nt(const float* __restrict__ A, int lda,
                        const float* __restrict__ B, int ldb,
                        float* __restrict__ C, int ldc,
                        int M, int N, int K, const float* __restrict__ bias)
{
    __shared__ float As[16][65];
    __shared__ float Bs[16][65];
    int m0 = blockIdx.y * 64, n0 = blockIdx.x * 64;
    int tid = threadIdx.x;
    int tx = tid & 15, ty = tid >> 4;
    float acc[4][4] = {};
    for (int k0 = 0; k0 < K; k0 += 16) {
        #pragma unroll
        for (int p = 0; p < 4; ++p) {
            int r = (tid >> 4) + p * 16;             // 0..63 (row of tile)
            int k = tid & 15;
            int gk = k0 + k;
            int gm = m0 + r;
            As[k][r] = (gm < M && gk < K) ? A[(long)gm * lda + gk] : 0.f;
            int gn = n0 + r;
            Bs[k][r] = (gn < N && gk < K) ? B[(long)gn * ldb + gk] : 0.f;
        }
        __syncthreads();
        #pragma unroll
        for (int k = 0; k < 16; ++k) {
            float a[4], b[4];
            #pragma unroll
            for (int i = 0; i < 4; ++i) a[i] = As[k][ty * 4 + i];
            #pragma unroll
            for (int j = 0; j < 4; ++j) b[j] = Bs[k][tx * 4 + j];
            #pragma unroll
            for (int i = 0; i < 4; ++i)
                #pragma unroll
                for (int j = 0; j < 4; ++j)
                    acc[i][j] += a[i] * b[j];
        }
        __syncthreads();
    }
    #pragma unroll
    for (int i = 0; i < 4; ++i) {
        int gm = m0 + ty * 4 + i;
        if (gm >= M) continue;
        #pragma unroll
        for (int j = 0; j < 4; ++j) {
            int gn = n0 + tx * 4 + j;
            if (gn >= N) continue;
            float v = acc[i][j];
            if (HAS_BIAS) v += bias[gn];
            if (DO_RELU) v = fmaxf(v, 0.f);
            C[(long)gm * ldc + gn] = v;
        }
    }
}

// ---- batched NN GEMM: C[m,n] = sum_k A[m,k]*B[k,n], batch via blockIdx.z ----
__global__ void gemm_nn(const float* __restrict__ A, int lda, long sA,
                        const float* __restrict__ B, int ldb, long sB,
                        float* __restrict__ C, int ldc, long sC,
                        int M, int N, int K)
{
    __shared__ float As[16][65];
    __shared__ float Bs[16][65];
    A += (long)blockIdx.z * sA;
    B += (long)blockIdx.z * sB;
    C += (long)blockIdx.z * sC;
    int m0 = blockIdx.y * 64, n0 = blockIdx.x * 64;
    int tid = threadIdx.x;
    int tx = tid & 15, ty = tid >> 4;
    float acc[4][4] = {};
    for (int k0 = 0; k0 < K; k0 += 16) {
        #pragma unroll
        for (int p = 0; p < 4; ++p) {
            int r = (tid >> 4) + p * 16;
            int k = tid & 15;
            int gk = k0 + k;
            int gm = m0 + r;
            As[k][r] = (gm < M && gk < K) ? A[(long)gm * lda + gk] : 0.f;
            int kk = (tid >> 6) + p * 4;             // 0..15
            int n  = tid & 63;
            int gk2 = k0 + kk, gn = n0 + n;
            Bs[kk][n] = (gk2 < K && gn < N) ? B[(long)gk2 * ldb + gn] : 0.f;
        }
        __syncthreads();
        #pragma unroll
        for (int k = 0; k < 16; ++k) {
            float a[4], b[4];
            #pragma unroll
            for (int i = 0; i < 4; ++i) a[i] = As[k][ty * 4 + i];
            #pragma unroll
            for (int j = 0; j < 4; ++j) b[j] = Bs[k][tx * 4 + j];
            #pragma unroll
            for (int i = 0; i < 4; ++i)
                #pragma unroll
                for (int j = 0; j < 4; ++j)
                    acc[i][j] += a[i] * b[j];
        }
        __syncthreads();
    }
    #pragma unroll
    for (int i = 0; i < 4; ++i) {
        int gm = m0 + ty * 4 + i;
        if (gm >= M) continue;
        #pragma unroll
        for (int j = 0; j < 4; ++j) {
            int gn = n0 + tx * 4 + j;
            if (gn >= N) continue;
            C[(long)gm * ldc + gn] = acc[i][j];
        }
    }
}

// ---- row means: xm[m] = mean_s xv1[m,s] ------------------------------------
__global__ void mean_k(const float* __restrict__ xv1, float* __restrict__ xm)
{
    int gid = blockIdx.x * 256 + threadIdx.x;
    int row = gid >> 6;                              // one wave per row
    int lane = threadIdx.x & 63;
    const float* r = xv1 + (long)row * 576;
    float a = 0.f;
    #pragma unroll
    for (int it = 0; it < 9; ++it) a += r[it * 64 + lane];
    #pragma unroll
    for (int off = 32; off; off >>= 1) a += __shfl_down(a, off, 64);
    if (lane == 0) xm[row] = a * (1.f / 576.f);
}

// ---- attention: At[(b,blk,d),c] = softmax_c exp(-(xm_c - xm_d)^2) ----------
// scores <= 0 with diagonal exactly 0 -> no max subtraction needed.
__global__ void attn_k(const float* __restrict__ xm, float* __restrict__ At)
{
    __shared__ float sxm[512];
    int grp = blockIdx.x, blk = blockIdx.y, b = blockIdx.z;
    const float* xb = xm + (b << 10) + (blk << 9);
    for (int i = threadIdx.x; i < 512; i += 256) sxm[i] = xb[i];
    __syncthreads();
    int wave = threadIdx.x >> 6, lane = threadIdx.x & 63;
    float* out = At + ((long)((b << 1) + blk) << 9) * 512;
    for (int dd = 0; dd < 16; ++dd) {
        int d = grp * 64 + wave * 16 + dd;
        float xd = sxm[d];
        float e[8];
        float sum = 0.f;
        #pragma unroll
        for (int it = 0; it < 8; ++it) {
            float df = sxm[it * 64 + lane] - xd;
            e[it] = __expf(-df * df);
            sum += e[it];
        }
        #pragma unroll
        for (int off = 32; off; off >>= 1) sum += __shfl_down(sum, off, 64);
        sum = __shfl(sum, 0, 64);
        float inv = 1.f / sum;
        #pragma unroll
        for (int it = 0; it < 8; ++it)
            out[(long)d * 512 + it * 64 + lane] = e[it] * inv;
    }
}

// ---- BN stats: stats[s] = sum over 65536 rows, stats[576+s] = sum of sq ----
__global__ void bnstat_k(const float* __restrict__ out3, float* __restrict__ stats)
{
    int s = threadIdx.x;                             // 0..575
    long r0 = (long)blockIdx.x * 256;
    float a = 0.f, a2 = 0.f;
    for (int r = 0; r < 256; ++r) {
        float v = out3[(r0 + r) * 576 + s];
        a += v; a2 += v * v;
    }
    atomicAdd(&stats[s], a);
    atomicAdd(&stats[576 + s], a2);
}

// ---- epilogue: out = relu(x + 0.25 * BN(out3)) scattered back --------------
__global__ void final_k(const float* __restrict__ x, const float* __restrict__ out3,
                        const float* __restrict__ stats,
                        const float* __restrict__ gamma, const float* __restrict__ beta,
                        float* __restrict__ out)
{
    int i = blockIdx.x * 256 + threadIdx.x;          // over 16*1024*48*48
    int xx = i % 48; int t = i / 48;
    int y = t % 48; t /= 48;
    int c = t & 1023; int n = t >> 10;
    int ti = (y / 24) * 2 + (xx / 24);
    int b = ti * 16 + n;
    int s = (y % 24) * 24 + (xx % 24);
    float mu = stats[s] * (1.f / 65536.f);
    float var = stats[576 + s] * (1.f / 65536.f) - mu * mu;
    float v = out3[(((long)b << 10) + c) * 576 + s];
    float bn = (v - mu) * rsqrtf(var + EPS) * gamma[s] + beta[s];
    out[i] = fmaxf(x[i] + 0.25f * bn, 0.f);
}

extern "C" void kernel_launch(void* const* d_in, const int* in_sizes, int n_in,
                              void* d_out, int out_size, void* d_ws, size_t ws_size,
                              hipStream_t stream)
{
    const float* x      = (const float*)d_in[0];
    const float* w_in1  = (const float*)d_in[1];
    const float* b_in1  = (const float*)d_in[2];
    const float* w_in2  = (const float*)d_in[3];
    const float* b_in2  = (const float*)d_in[4];
    const float* w_out1 = (const float*)d_in[5];
    const float* b_out1 = (const float*)d_in[6];
    const float* w_out2 = (const float*)d_in[7];
    const float* b_out2 = (const float*)d_in[8];
    const float* gamma  = (const float*)d_in[9];
    const float* beta   = (const float*)d_in[10];
    float* out = (float*)d_out;

    char* ws = (char*)d_ws;
    float* xv0   = (float*)(ws);
    float* xv1   = (float*)(ws + 150994944L);
    float* Hbuf  = (float*)(ws + 301989888L);
    float* At    = (float*)(ws + 320864256L);
    float* xm    = (float*)(ws + 455081984L);
    float* stats = (float*)(ws + 455344128L);
    float* out2 = xv0;   // xv0 dead after MLP1a
    float* out3 = xv1;   // xv1 dead after bmm

    hipMemsetAsync(stats, 0, 1152 * sizeof(float), stream);

    // gather patches -> (B,C,S)
    extract_k<<<147456, 256, 0, stream>>>(x, xv0);

    // MLP1: H = relu(xv0 @ w_in1^T + b_in1)   [65536x576 @ 576x72]
    gemm_nt<1,1><<<dim3(2, 1024), 256, 0, stream>>>(
        xv0, 576, w_in1, 576, Hbuf, 72, 65536, 72, 576, b_in1);
    //        xv1 = H @ w_in2^T + b_in2        [65536x72 @ 72x576]
    gemm_nt<0,1><<<dim3(9, 1024), 256, 0, stream>>>(
        Hbuf, 72, w_in2, 72, xv1, 576, 65536, 576, 72, b_in2);

    // channel means over s
    mean_k<<<16384, 256, 0, stream>>>(xv1, xm);

    // block-diagonal softmax attention (transposed storage)
    attn_k<<<dim3(8, 2, 64), 256, 0, stream>>>(xm, At);

    // bmm: out2[(b,blk*512+d), s] = sum_c At[d,c] * xv1[(b,blk*512+c), s]
    gemm_nn<<<dim3(9, 8, 128), 256, 0, stream>>>(
        At, 512, 262144L, xv1, 576, 294912L, out2, 576, 294912L, 512, 576, 512);

    // MLP2
    gemm_nt<1,1><<<dim3(2, 1024), 256, 0, stream>>>(
        out2, 576, w_out1, 576, Hbuf, 72, 65536, 72, 576, b_out1);
    gemm_nt<0,1><<<dim3(9, 1024), 256, 0, stream>>>(
        Hbuf, 72, w_out2, 72, out3, 576, 65536, 576, 72, b_out2);

    // BatchNorm stats (sum, sumsq per s over 65536 rows)
    bnstat_k<<<256, 576, 0, stream>>>(out3, stats);

    // BN + scatter-add*0.25 + relu
    final_k<<<147456, 256, 0, stream>>>(x, out3, stats, gamma, beta, out);
}

// Round 2
// 703.323 us; speedup vs baseline: 2.9970x; 2.9970x over previous
//
#include <hip/hip_runtime.h>
#include <hip/hip_bf16.h>

// ============================================================================
// CrossNeuronBlock — bf16 MFMA pipeline (m97-structure GEMMs), fp32 glue.
//
// B=64 chunk-batches, S=576, C=1024, H=72 (padded to 96), 2 blocks of 512.
// All activations bf16 row-major (M x cols); all GEMMs are NT with K
// contiguous on both operands, 128x128 tile, BK=32, 16x16x32 bf16 MFMA,
// global_load_lds width-16 staging. fp32: xm, softmax, BN stats, epilogue.
//
// ws layout (bytes, all 256-aligned):
//   xv0  @ 0          75,497,472   (reused as out2)
//   Hp   @ 75497472   12,582,912
//   xv1  @ 88080384   75,497,472   (reused as out3)
//   xv1T @ 163577856  83,886,080   (128 x 640 x 512, s-pad zeroed)
//   At   @ 247463936  67,108,864
//   xm   @ 314572800     262,144
//   stats@ 314834944       4,608
//   w1p  @ 314839552     147,456   (128x576, rows>=72 zero)
//   w1op @ 314987008     147,456
//   w2p  @ 315134464     122,880   (640x96, pads zero)
//   w2op @ 315257344     122,880
//   b1p  @ 315380224         512
//   b1op @ 315380736         512
// ============================================================================

#define EPS 1e-5f

typedef __attribute__((ext_vector_type(8))) short short8;
typedef __attribute__((ext_vector_type(4))) float f32x4;

#define GLD_LDS(g, l) __builtin_amdgcn_global_load_lds( \
    (const __attribute__((address_space(1))) void*)(g), \
    (__attribute__((address_space(3))) void*)(l), 16, 0, 0)

// ---- weight/bias prep: bf16 + zero-padding ---------------------------------
__global__ void prep_k(const float* __restrict__ w_in1, const float* __restrict__ b_in1,
                       const float* __restrict__ w_in2,
                       const float* __restrict__ w_out1, const float* __restrict__ b_out1,
                       const float* __restrict__ w_out2,
                       __hip_bfloat16* __restrict__ w1p, __hip_bfloat16* __restrict__ w1op,
                       __hip_bfloat16* __restrict__ w2p, __hip_bfloat16* __restrict__ w2op,
                       float* __restrict__ b1p, float* __restrict__ b1op)
{
    int i = blockIdx.x * 256 + threadIdx.x;
    if (i < 128 * 576) {
        int r = i / 576, c = i - r * 576;
        w1p[i]  = __float2bfloat16(r < 72 ? w_in1[r * 576 + c] : 0.f);
        w1op[i] = __float2bfloat16(r < 72 ? w_out1[r * 576 + c] : 0.f);
    }
    if (i < 640 * 96) {
        int r = i / 96, c = i - r * 96;
        bool ok = (r < 576) && (c < 72);
        w2p[i]  = __float2bfloat16(ok ? w_in2[r * 72 + c] : 0.f);
        w2op[i] = __float2bfloat16(ok ? w_out2[r * 72 + c] : 0.f);
    }
    if (i < 128) {
        b1p[i]  = i < 72 ? b_in1[i] : 0.f;
        b1op[i] = i < 72 ? b_out1[i] : 0.f;
    }
}

// ---- gather x -> xv0 bf16 [(b*1024+c)*576 + s] ------------------------------
__global__ void extract_k(const float* __restrict__ x, __hip_bfloat16* __restrict__ xv)
{
    int i = blockIdx.x * 256 + threadIdx.x;          // 0 .. 37,748,735
    int s = i % 576;
    int m = i / 576;
    int c = m & 1023;
    int b = m >> 10;
    int n = b & 15, ti = b >> 4;
    int ty = (ti >> 1) * 24, tx = (ti & 1) * 24;
    int sy = s / 24, sx = s - sy * 24;
    xv[i] = __float2bfloat16(x[(((n << 10) + c) * 48 + ty + sy) * 48 + tx + sx]);
}

// ---- NT bf16 MFMA GEMM (m97 structure): C[m,n] = sum_k A[m,k]*B[n,k] --------
// M multiple of 128 (grid.y), K multiple of 32, B allocated >= gridDim.x*128
// rows (zero-padded); stores masked by n < N. fp32 accum, bf16 out.
template<int HAS_BIAS, int DO_RELU>
__global__ __launch_bounds__(256) void gemm_bf16(
    const unsigned short* __restrict__ A, int lda, long sA,
    const unsigned short* __restrict__ B, int ldb, long sB,
    __hip_bfloat16* __restrict__ C, int ldc, long sC,
    int N, int K, const float* __restrict__ bias)
{
    __shared__ unsigned short As[128 * 32];
    __shared__ unsigned short Bs[128 * 32];
    A += (long)blockIdx.z * sA;
    B += (long)blockIdx.z * sB;
    C += (long)blockIdx.z * sC;
    const int m0 = blockIdx.y * 128, n0 = blockIdx.x * 128;
    const int t = threadIdx.x;
    const int lane = t & 63, wave = t >> 6;
    const int wr = wave >> 1, wc = wave & 1;
    const int lrow = lane & 15, kq = (lane >> 4) * 8;
    const int r0 = t >> 2, c0 = (t & 3) * 8;         // staging chunk coords

    f32x4 acc[4][4];
    #pragma unroll
    for (int i = 0; i < 4; ++i)
        #pragma unroll
        for (int j = 0; j < 4; ++j)
            acc[i][j] = (f32x4){0.f, 0.f, 0.f, 0.f};

    for (int k0 = 0; k0 < K; k0 += 32) {
        GLD_LDS(A + (long)(m0 + r0) * lda + k0 + c0,      &As[t * 8]);
        GLD_LDS(A + (long)(m0 + r0 + 64) * lda + k0 + c0, &As[(t + 256) * 8]);
        GLD_LDS(B + (long)(n0 + r0) * ldb + k0 + c0,      &Bs[t * 8]);
        GLD_LDS(B + (long)(n0 + r0 + 64) * ldb + k0 + c0, &Bs[(t + 256) * 8]);
        __syncthreads();
        short8 af[4], bf[4];
        #pragma unroll
        for (int i = 0; i < 4; ++i)
            af[i] = *(const short8*)&As[(wr * 64 + i * 16 + lrow) * 32 + kq];
        #pragma unroll
        for (int j = 0; j < 4; ++j)
            bf[j] = *(const short8*)&Bs[(wc * 64 + j * 16 + lrow) * 32 + kq];
        #pragma unroll
        for (int i = 0; i < 4; ++i)
            #pragma unroll
            for (int j = 0; j < 4; ++j)
                acc[i][j] = __builtin_amdgcn_mfma_f32_16x16x32_bf16(af[i], bf[j], acc[i][j], 0, 0, 0);
        __syncthreads();
    }

    const int cr = (lane >> 4) * 4;                  // C/D: col=lane&15, row=quad*4+reg
    #pragma unroll
    for (int j = 0; j < 4; ++j) {
        int col = n0 + wc * 64 + j * 16 + lrow;
        if (col >= N) continue;
        float bv = HAS_BIAS ? bias[col] : 0.f;
        #pragma unroll
        for (int i = 0; i < 4; ++i) {
            long rowb = (long)(m0 + wr * 64 + i * 16 + cr) * ldc;
            #pragma unroll
            for (int r = 0; r < 4; ++r) {
                float v = acc[i][j][r] + bv;
                if (DO_RELU) v = fmaxf(v, 0.f);
                C[rowb + (long)r * ldc + col] = __float2bfloat16(v);
            }
        }
    }
}

// ---- row means (fp32): xm[m] = mean_s xv1[m,s] ------------------------------
__global__ void mean_k(const __hip_bfloat16* __restrict__ xv1, float* __restrict__ xm)
{
    int gid = blockIdx.x * 256 + threadIdx.x;
    int row = gid >> 6;
    int lane = threadIdx.x & 63;
    const __hip_bfloat16* r = xv1 + (long)row * 576;
    float a = 0.f;
    #pragma unroll
    for (int it = 0; it < 9; ++it) a += __bfloat162float(r[it * 64 + lane]);
    #pragma unroll
    for (int off = 32; off; off >>= 1) a += __shfl_down(a, off, 64);
    if (lane == 0) xm[row] = a * (1.f / 576.f);
}

// ---- attention (fp32 math, bf16 out): At[(b,blk,d),c] ----------------------
__global__ void attn_k(const float* __restrict__ xm, __hip_bfloat16* __restrict__ At)
{
    __shared__ float sxm[512];
    int grp = blockIdx.x, blk = blockIdx.y, b = blockIdx.z;
    const float* xb = xm + (b << 10) + (blk << 9);
    for (int i = threadIdx.x; i < 512; i += 256) sxm[i] = xb[i];
    __syncthreads();
    int wave = threadIdx.x >> 6, lane = threadIdx.x & 63;
    __hip_bfloat16* out = At + ((long)((b << 1) + blk) << 9) * 512;
    for (int dd = 0; dd < 16; ++dd) {
        int d = grp * 64 + wave * 16 + dd;
        float xd = sxm[d];
        float e[8];
        float sum = 0.f;
        #pragma unroll
        for (int it = 0; it < 8; ++it) {
            float df = sxm[it * 64 + lane] - xd;
            e[it] = __expf(-df * df);
            sum += e[it];
        }
        #pragma unroll
        for (int off = 32; off; off >>= 1) sum += __shfl_down(sum, off, 64);
        sum = __shfl(sum, 0, 64);
        float inv = 1.f / sum;
        #pragma unroll
        for (int it = 0; it < 8; ++it)
            out[(long)d * 512 + it * 64 + lane] = __float2bfloat16(e[it] * inv);
    }
}

// ---- transpose per (b,blk): xv1 (512 rows x 576) -> xv1T (640 x 512) -------
__global__ void transpose_k(const __hip_bfloat16* __restrict__ xv1,
                            __hip_bfloat16* __restrict__ xv1T)
{
    __shared__ __hip_bfloat16 tile[32][33];
    int z = blockIdx.z;                              // 0..127
    int c0 = blockIdx.x * 32;                        // 0..480
    int s0 = blockIdx.y * 32;                        // 0..608
    int tj = threadIdx.x & 31, ti = threadIdx.x >> 5;
    #pragma unroll
    for (int p = 0; p < 4; ++p) {
        int i = ti + p * 8;
        int s = s0 + tj;
        tile[i][tj] = (s < 576)
            ? xv1[((long)(z * 512 + c0 + i)) * 576 + s]
            : __float2bfloat16(0.f);
    }
    __syncthreads();
    #pragma unroll
    for (int p = 0; p < 4; ++p) {
        int srow = ti + p * 8;
        xv1T[((long)z * 640 + s0 + srow) * 512 + c0 + tj] = tile[tj][srow];
    }
}

// ---- BN stats (fp32): sum & sumsq per s over 65536 rows --------------------
__global__ void bnstat_k(const __hip_bfloat16* __restrict__ out3, float* __restrict__ stats)
{
    int s = threadIdx.x;                             // 0..575
    long r0 = (long)blockIdx.x * 256;
    float a = 0.f, a2 = 0.f;
    for (int r = 0; r < 256; ++r) {
        float v = __bfloat162float(out3[(r0 + r) * 576 + s]);
        a += v; a2 += v * v;
    }
    atomicAdd(&stats[s], a);
    atomicAdd(&stats[576 + s], a2);
}

// ---- epilogue: out = relu(x + 0.25 * BN(out3)) -----------------------------
__global__ void final_k(const float* __restrict__ x, const __hip_bfloat16* __restrict__ out3,
                        const float* __restrict__ stats,
                        const float* __restrict__ gamma, const float* __restrict__ beta,
                        float* __restrict__ out)
{
    int i = blockIdx.x * 256 + threadIdx.x;
    int xx = i % 48; int t = i / 48;
    int y = t % 48; t /= 48;
    int c = t & 1023; int n = t >> 10;
    int ti = (y / 24) * 2 + (xx / 24);
    int b = ti * 16 + n;
    int s = (y % 24) * 24 + (xx % 24);
    float mu = stats[s] * (1.f / 65536.f);
    float var = stats[576 + s] * (1.f / 65536.f) - mu * mu;
    float v = __bfloat162float(out3[(((long)b << 10) + c) * 576 + s]);
    float bn = (v - mu) * rsqrtf(var + EPS) * gamma[s] + beta[s];
    out[i] = fmaxf(x[i] + 0.25f * bn, 0.f);
}

extern "C" void kernel_launch(void* const* d_in, const int* in_sizes, int n_in,
                              void* d_out, int out_size, void* d_ws, size_t ws_size,
                              hipStream_t stream)
{
    const float* x      = (const float*)d_in[0];
    const float* w_in1  = (const float*)d_in[1];
    const float* b_in1  = (const float*)d_in[2];
    const float* w_in2  = (const float*)d_in[3];
    const float* b_in2  = (const float*)d_in[4];
    const float* w_out1 = (const float*)d_in[5];
    const float* b_out1 = (const float*)d_in[6];
    const float* w_out2 = (const float*)d_in[7];
    const float* b_out2 = (const float*)d_in[8];
    const float* gamma  = (const float*)d_in[9];
    const float* beta   = (const float*)d_in[10];
    float* out = (float*)d_out;

    char* ws = (char*)d_ws;
    __hip_bfloat16* xv0   = (__hip_bfloat16*)(ws);
    __hip_bfloat16* Hp    = (__hip_bfloat16*)(ws + 75497472L);
    __hip_bfloat16* xv1   = (__hip_bfloat16*)(ws + 88080384L);
    __hip_bfloat16* xv1T  = (__hip_bfloat16*)(ws + 163577856L);
    __hip_bfloat16* At    = (__hip_bfloat16*)(ws + 247463936L);
    float*          xm    = (float*)(ws + 314572800L);
    float*          stats = (float*)(ws + 314834944L);
    __hip_bfloat16* w1p   = (__hip_bfloat16*)(ws + 314839552L);
    __hip_bfloat16* w1op  = (__hip_bfloat16*)(ws + 314987008L);
    __hip_bfloat16* w2p   = (__hip_bfloat16*)(ws + 315134464L);
    __hip_bfloat16* w2op  = (__hip_bfloat16*)(ws + 315257344L);
    float*          b1p   = (float*)(ws + 315380224L);
    float*          b1op  = (float*)(ws + 315380736L);
    __hip_bfloat16* out2  = xv0;   // xv0 dead after MLP1a
    __hip_bfloat16* out3  = xv1;   // xv1 dead after transpose

    hipMemsetAsync(stats, 0, 1152 * sizeof(float), stream);

    prep_k<<<288, 256, 0, stream>>>(w_in1, b_in1, w_in2, w_out1, b_out1, w_out2,
                                    w1p, w1op, w2p, w2op, b1p, b1op);

    extract_k<<<147456, 256, 0, stream>>>(x, xv0);

    // MLP1a: Hp = relu(xv0 @ w1p^T + b1p)   M=65536 N=96 K=576
    gemm_bf16<1,1><<<dim3(1, 512, 1), 256, 0, stream>>>(
        (const unsigned short*)xv0, 576, 0L, (const unsigned short*)w1p, 576, 0L,
        Hp, 96, 0L, 96, 576, b1p);
    // MLP1b: xv1 = Hp @ w2p^T + b_in2       M=65536 N=576 K=96
    gemm_bf16<1,0><<<dim3(5, 512, 1), 256, 0, stream>>>(
        (const unsigned short*)Hp, 96, 0L, (const unsigned short*)w2p, 96, 0L,
        xv1, 576, 0L, 576, 96, b_in2);

    mean_k<<<16384, 256, 0, stream>>>(xv1, xm);
    attn_k<<<dim3(8, 2, 64), 256, 0, stream>>>(xm, At);
    transpose_k<<<dim3(16, 20, 128), 256, 0, stream>>>(xv1, xv1T);

    // bmm: out2 = At @ xv1T^T  per z=128   M=512 N=576 K=512
    gemm_bf16<0,0><<<dim3(5, 4, 128), 256, 0, stream>>>(
        (const unsigned short*)At, 512, 262144L, (const unsigned short*)xv1T, 512, 327680L,
        out2, 576, 294912L, 576, 512, nullptr);

    // MLP2a: Hp = relu(out2 @ w1op^T + b1op)
    gemm_bf16<1,1><<<dim3(1, 512, 1), 256, 0, stream>>>(
        (const unsigned short*)out2, 576, 0L, (const unsigned short*)w1op, 576, 0L,
        Hp, 96, 0L, 96, 576, b1op);
    // MLP2b: out3 = Hp @ w2op^T + b_out2
    gemm_bf16<1,0><<<dim3(5, 512, 1), 256, 0, stream>>>(
        (const unsigned short*)Hp, 96, 0L, (const unsigned short*)w2op, 96, 0L,
        out3, 576, 0L, 576, 96, b_out2);

    bnstat_k<<<256, 576, 0, stream>>>(out3, stats);
    final_k<<<147456, 256, 0, stream>>>(x, out3, stats, gamma, beta, out);
}

// Round 3
// 580.281 us; speedup vs baseline: 3.6325x; 1.2120x over previous
//
#include <hip/hip_runtime.h>
#include <hip/hip_bf16.h>

// ============================================================================
// CrossNeuronBlock — round 3: fusion.
//   extract(v4) -> MLP1a -> MLP1b(+transposed store to xv1T, +row-mean atomics)
//   -> denom_k (softmax denominators from means) -> gemm_attn (A computed
//   on the fly, no At buffer, XCD swizzle) -> MLP2a -> MLP2b(+BN col stats)
//   -> bnfin -> final(v4)
// B=64 chunks, S=576, C=1024, H=72->96pad, 2 blocks of 512. All GEMMs:
// 128x128 tile, BK=32, mfma 16x16x32 bf16, global_load_lds w16, fp32 accum.
// ============================================================================

#define EPS 1e-5f

typedef __attribute__((ext_vector_type(8))) short short8;
typedef __attribute__((ext_vector_type(4))) short short4v;
typedef __attribute__((ext_vector_type(4))) float f32x4;
typedef __attribute__((ext_vector_type(4))) float float4v;

#define GLD_LDS(g, l) __builtin_amdgcn_global_load_lds( \
    (const __attribute__((address_space(1))) void*)(g), \
    (__attribute__((address_space(3))) void*)(l), 16, 0, 0)

static __device__ __forceinline__ unsigned short f2bu(float f) {
    union { __hip_bfloat16 h; unsigned short u; } cv;
    cv.h = __float2bfloat16(f);
    return cv.u;
}
static __device__ __forceinline__ float bu2f(unsigned short u) {
    union { __hip_bfloat16 h; unsigned short u; } cv;
    cv.u = u;
    return __bfloat162float(cv.h);
}

// ---- weight/bias prep: bf16 + zero-padding ---------------------------------
__global__ void prep_k(const float* __restrict__ w_in1, const float* __restrict__ b_in1,
                       const float* __restrict__ w_in2,
                       const float* __restrict__ w_out1, const float* __restrict__ b_out1,
                       const float* __restrict__ w_out2,
                       __hip_bfloat16* __restrict__ w1p, __hip_bfloat16* __restrict__ w1op,
                       __hip_bfloat16* __restrict__ w2p, __hip_bfloat16* __restrict__ w2op,
                       float* __restrict__ b1p, float* __restrict__ b1op)
{
    int i = blockIdx.x * 256 + threadIdx.x;
    if (i < 128 * 576) {
        int r = i / 576, c = i - r * 576;
        w1p[i]  = __float2bfloat16(r < 72 ? w_in1[r * 576 + c] : 0.f);
        w1op[i] = __float2bfloat16(r < 72 ? w_out1[r * 576 + c] : 0.f);
    }
    if (i < 640 * 96) {
        int r = i / 96, c = i - r * 96;
        bool ok = (r < 576) && (c < 72);
        w2p[i]  = __float2bfloat16(ok ? w_in2[r * 72 + c] : 0.f);
        w2op[i] = __float2bfloat16(ok ? w_out2[r * 72 + c] : 0.f);
    }
    if (i < 128) {
        b1p[i]  = i < 72 ? b_in1[i] : 0.f;
        b1op[i] = i < 72 ? b_out1[i] : 0.f;
    }
}

// ---- gather x -> xv0 bf16, float4 loads / short4 stores --------------------
__global__ void extract_k(const float4v* __restrict__ x4, __hip_bfloat16* __restrict__ xv)
{
    int i = blockIdx.x * 256 + threadIdx.x;          // 0 .. 9,437,183
    int s4 = i % 144;                                // 576/4 vec4 per row
    int m = i / 144;
    int c = m & 1023;
    int b = m >> 10;
    int n = b & 15, ti = b >> 4;
    int ty = (ti >> 1) * 24, tx = (ti & 1) * 24;
    int s = s4 * 4;
    int sy = s / 24, sx = s - sy * 24;
    float4v v = x4[((((n << 10) + c) * 48 + ty + sy) * 48 + tx + sx) >> 2];
    short4v pk;
    pk.x = (short)f2bu(v.x); pk.y = (short)f2bu(v.y);
    pk.z = (short)f2bu(v.z); pk.w = (short)f2bu(v.w);
    *(short4v*)(xv + (long)i * 4) = pk;
}

// ---- plain NT bf16 MFMA GEMM (m97 structure) -------------------------------
template<int HAS_BIAS, int DO_RELU>
__global__ __launch_bounds__(256) void gemm_bf16(
    const unsigned short* __restrict__ A, int lda,
    const unsigned short* __restrict__ B, int ldb,
    __hip_bfloat16* __restrict__ C, int ldc,
    int N, int K, const float* __restrict__ bias)
{
    __shared__ unsigned short As[128 * 32];
    __shared__ unsigned short Bs[128 * 32];
    const int m0 = blockIdx.y * 128, n0 = blockIdx.x * 128;
    const int t = threadIdx.x;
    const int lane = t & 63, wave = t >> 6;
    const int wr = wave >> 1, wc = wave & 1;
    const int lrow = lane & 15, kq = (lane >> 4) * 8;
    const int r0 = t >> 2, c0 = (t & 3) * 8;

    f32x4 acc[4][4];
    #pragma unroll
    for (int i = 0; i < 4; ++i)
        #pragma unroll
        for (int j = 0; j < 4; ++j)
            acc[i][j] = (f32x4){0.f, 0.f, 0.f, 0.f};

    for (int k0 = 0; k0 < K; k0 += 32) {
        GLD_LDS(A + (long)(m0 + r0) * lda + k0 + c0,      &As[t * 8]);
        GLD_LDS(A + (long)(m0 + r0 + 64) * lda + k0 + c0, &As[(t + 256) * 8]);
        GLD_LDS(B + (long)(n0 + r0) * ldb + k0 + c0,      &Bs[t * 8]);
        GLD_LDS(B + (long)(n0 + r0 + 64) * ldb + k0 + c0, &Bs[(t + 256) * 8]);
        __syncthreads();
        short8 af[4], bf[4];
        #pragma unroll
        for (int i = 0; i < 4; ++i)
            af[i] = *(const short8*)&As[(wr * 64 + i * 16 + lrow) * 32 + kq];
        #pragma unroll
        for (int j = 0; j < 4; ++j)
            bf[j] = *(const short8*)&Bs[(wc * 64 + j * 16 + lrow) * 32 + kq];
        #pragma unroll
        for (int i = 0; i < 4; ++i)
            #pragma unroll
            for (int j = 0; j < 4; ++j)
                acc[i][j] = __builtin_amdgcn_mfma_f32_16x16x32_bf16(af[i], bf[j], acc[i][j], 0, 0, 0);
        __syncthreads();
    }

    const int cr = (lane >> 4) * 4;
    #pragma unroll
    for (int j = 0; j < 4; ++j) {
        int col = n0 + wc * 64 + j * 16 + lrow;
        if (col >= N) continue;
        float bv = HAS_BIAS ? bias[col] : 0.f;
        #pragma unroll
        for (int i = 0; i < 4; ++i) {
            long rowb = (long)(m0 + wr * 64 + i * 16 + cr) * ldc;
            #pragma unroll
            for (int r = 0; r < 4; ++r) {
                float v = acc[i][j][r] + bv;
                if (DO_RELU) v = fmaxf(v, 0.f);
                C[rowb + (long)r * ldc + col] = __float2bfloat16(v);
            }
        }
    }
}

// ---- MLP1b: NT GEMM, transposed store -> xv1T + row-mean atomics -----------
// A = Hp (65536 x 96), B = w2p (640 x 96), out rows m=(b,c), cols n=s.
// Stores xv1T[(z*640 + s)*512 + c_local] (z = m0>>9), skips s>=576 cols.
// atomicAdd raw row sums (no bias; pad cols contribute exactly 0) to xm_raw.
__global__ __launch_bounds__(256) void gemm_t(
    const unsigned short* __restrict__ A, int lda,
    const unsigned short* __restrict__ B, int ldb,
    __hip_bfloat16* __restrict__ xv1T,
    int K, const float* __restrict__ bias, float* __restrict__ xm_raw)
{
    __shared__ unsigned short smem[128 * 129];       // >= As(4096)+Bs(4096)
    unsigned short* As = smem;
    unsigned short* Bs = smem + 4096;
    const int m0 = blockIdx.y * 128, n0 = blockIdx.x * 128;
    const int z = m0 >> 9, m_local = m0 & 511;
    const int t = threadIdx.x;
    const int lane = t & 63, wave = t >> 6;
    const int wr = wave >> 1, wc = wave & 1;
    const int lrow = lane & 15, kq = (lane >> 4) * 8;
    const int r0 = t >> 2, c0 = (t & 3) * 8;

    f32x4 acc[4][4];
    #pragma unroll
    for (int i = 0; i < 4; ++i)
        #pragma unroll
        for (int j = 0; j < 4; ++j)
            acc[i][j] = (f32x4){0.f, 0.f, 0.f, 0.f};

    for (int k0 = 0; k0 < K; k0 += 32) {
        GLD_LDS(A + (long)(m0 + r0) * lda + k0 + c0,      &As[t * 8]);
        GLD_LDS(A + (long)(m0 + r0 + 64) * lda + k0 + c0, &As[(t + 256) * 8]);
        GLD_LDS(B + (long)(n0 + r0) * ldb + k0 + c0,      &Bs[t * 8]);
        GLD_LDS(B + (long)(n0 + r0 + 64) * ldb + k0 + c0, &Bs[(t + 256) * 8]);
        __syncthreads();
        short8 af[4], bf[4];
        #pragma unroll
        for (int i = 0; i < 4; ++i)
            af[i] = *(const short8*)&As[(wr * 64 + i * 16 + lrow) * 32 + kq];
        #pragma unroll
        for (int j = 0; j < 4; ++j)
            bf[j] = *(const short8*)&Bs[(wc * 64 + j * 16 + lrow) * 32 + kq];
        #pragma unroll
        for (int i = 0; i < 4; ++i)
            #pragma unroll
            for (int j = 0; j < 4; ++j)
                acc[i][j] = __builtin_amdgcn_mfma_f32_16x16x32_bf16(af[i], bf[j], acc[i][j], 0, 0, 0);
        __syncthreads();
    }

    const int cr = (lane >> 4) * 4;

    // row-mean partials: sum over this block's 128 cols (pad cols are 0)
    #pragma unroll
    for (int i = 0; i < 4; ++i)
        #pragma unroll
        for (int r = 0; r < 4; ++r) {
            float v = acc[i][0][r] + acc[i][1][r] + acc[i][2][r] + acc[i][3][r];
            v += __shfl_xor(v, 1, 64);
            v += __shfl_xor(v, 2, 64);
            v += __shfl_xor(v, 4, 64);
            v += __shfl_xor(v, 8, 64);
            if (lrow == 0)
                atomicAdd(&xm_raw[m0 + wr * 64 + i * 16 + cr + r], v);
        }

    // C tile (+bias) into LDS [row_c 128][col_s 129]
    #pragma unroll
    for (int j = 0; j < 4; ++j) {
        int col = wc * 64 + j * 16 + lrow;
        float bv = (n0 + col < 576) ? bias[n0 + col] : 0.f;
        #pragma unroll
        for (int i = 0; i < 4; ++i) {
            int row = wr * 64 + i * 16 + cr;
            #pragma unroll
            for (int r = 0; r < 4; ++r)
                smem[(row + r) * 129 + col] = f2bu(acc[i][j][r] + bv);
        }
    }
    __syncthreads();

    // transposed, coalesced store: thread -> (s-row, 64 c-elements)
    int s_r = t >> 1, chalf = (t & 1) * 64;
    if (n0 + s_r < 576) {
        __hip_bfloat16* dst = xv1T + ((long)z * 640 + n0 + s_r) * 512 + m_local + chalf;
        #pragma unroll
        for (int v8 = 0; v8 < 8; ++v8) {
            short8 pk;
            #pragma unroll
            for (int e = 0; e < 8; ++e)
                pk[e] = (short)smem[(chalf + v8 * 8 + e) * 129 + s_r];
            *(short8*)(dst + v8 * 8) = pk;
        }
    }
}

// ---- denom: normalized means + softmax denominators ------------------------
__global__ void denom_k(const float* __restrict__ xm_raw, const float* __restrict__ b_in2,
                        float* __restrict__ xmn, float* __restrict__ invd)
{
    __shared__ float sx[512];
    __shared__ float red[256];
    int z = blockIdx.x;                              // (b,blk) 0..127
    int t = threadIdx.x;
    float p = 0.f;
    for (int i = t; i < 576; i += 256) p += b_in2[i];
    red[t] = p; __syncthreads();
    for (int o = 128; o; o >>= 1) { if (t < o) red[t] += red[t + o]; __syncthreads(); }
    float btot = red[0];
    for (int i = t; i < 512; i += 256) {
        float m = (xm_raw[(long)z * 512 + i] + btot) * (1.f / 576.f);
        sx[i] = m;
        xmn[(long)z * 512 + i] = m;
    }
    __syncthreads();
    #pragma unroll
    for (int dd = 0; dd < 2; ++dd) {
        int d = t + dd * 256;
        float xd = sx[d], s = 0.f;
        for (int c = 0; c < 512; ++c) { float df = sx[c] - xd; s += __expf(-df * df); }
        invd[(long)z * 512 + d] = 1.f / s;
    }
}

// ---- fused attention bmm: A computed on the fly, B = xv1T ------------------
// out2[(z*512+d), s] = sum_c At[d,c] * xv1T[z][s][c],
// At[d,c] = exp(-(xmn_c - xmn_d)^2) * invd[d].
__global__ __launch_bounds__(256) void gemm_attn(
    const unsigned short* __restrict__ Bg,
    const float* __restrict__ xmn, const float* __restrict__ invd,
    __hip_bfloat16* __restrict__ C)
{
    __shared__ unsigned short As[128 * 32];
    __shared__ unsigned short Bs[128 * 32];
    __shared__ float sxm[512];
    __shared__ float sinv[128];
    // XCD-aware swizzle: 4 m-tiles sharing a B-strip -> same XCD (ids g,g+8,..)
    int g = blockIdx.x;
    int xcd = g & 7, idx = g >> 3;
    int y = idx & 3;
    int combo = (idx >> 2) * 8 + xcd;                // 0..639
    int nx = combo % 5, z = combo / 5;
    const int m0 = y * 128, n0 = nx * 128;
    const int t = threadIdx.x;
    const int lane = t & 63, wave = t >> 6;
    const int wr = wave >> 1, wc = wave & 1;
    const int lrow = lane & 15, kq = (lane >> 4) * 8;
    const int r0 = t >> 2, c0 = (t & 3) * 8;
    const unsigned short* B = Bg + (long)z * 640 * 512;
    __hip_bfloat16* Cz = C + (long)z * 512 * 576;

    for (int i = t; i < 512; i += 256) sxm[i] = xmn[(long)z * 512 + i];
    if (t < 128) sinv[t] = invd[(long)z * 512 + m0 + t];
    __syncthreads();

    const int dA = t >> 1, cbA = (t & 1) * 16;       // A-tile compute coords
    const float xd = sxm[m0 + dA];
    const float ivd = sinv[dA];

    f32x4 acc[4][4];
    #pragma unroll
    for (int i = 0; i < 4; ++i)
        #pragma unroll
        for (int j = 0; j < 4; ++j)
            acc[i][j] = (f32x4){0.f, 0.f, 0.f, 0.f};

    for (int k0 = 0; k0 < 512; k0 += 32) {
        GLD_LDS(B + (long)(n0 + r0) * 512 + k0 + c0,      &Bs[t * 8]);
        GLD_LDS(B + (long)(n0 + r0 + 64) * 512 + k0 + c0, &Bs[(t + 256) * 8]);
        short8 pk0, pk1;
        #pragma unroll
        for (int e = 0; e < 8; ++e) {
            float d0 = sxm[k0 + cbA + e] - xd;
            pk0[e] = (short)f2bu(__expf(-d0 * d0) * ivd);
            float d1 = sxm[k0 + cbA + 8 + e] - xd;
            pk1[e] = (short)f2bu(__expf(-d1 * d1) * ivd);
        }
        *(short8*)&As[dA * 32 + cbA]     = pk0;
        *(short8*)&As[dA * 32 + cbA + 8] = pk1;
        __syncthreads();
        short8 af[4], bf[4];
        #pragma unroll
        for (int i = 0; i < 4; ++i)
            af[i] = *(const short8*)&As[(wr * 64 + i * 16 + lrow) * 32 + kq];
        #pragma unroll
        for (int j = 0; j < 4; ++j)
            bf[j] = *(const short8*)&Bs[(wc * 64 + j * 16 + lrow) * 32 + kq];
        #pragma unroll
        for (int i = 0; i < 4; ++i)
            #pragma unroll
            for (int j = 0; j < 4; ++j)
                acc[i][j] = __builtin_amdgcn_mfma_f32_16x16x32_bf16(af[i], bf[j], acc[i][j], 0, 0, 0);
        __syncthreads();
    }

    const int cr = (lane >> 4) * 4;
    #pragma unroll
    for (int j = 0; j < 4; ++j) {
        int col = n0 + wc * 64 + j * 16 + lrow;
        if (col >= 576) continue;
        #pragma unroll
        for (int i = 0; i < 4; ++i) {
            long rowb = (long)(m0 + wr * 64 + i * 16 + cr) * 576;
            #pragma unroll
            for (int r = 0; r < 4; ++r)
                Cz[rowb + (long)r * 576 + col] = __float2bfloat16(acc[i][j][r]);
        }
    }
}

// ---- MLP2b: NT GEMM + bias + BN column-stat atomics ------------------------
__global__ __launch_bounds__(256) void gemm_bn(
    const unsigned short* __restrict__ A, int lda,
    const unsigned short* __restrict__ B, int ldb,
    __hip_bfloat16* __restrict__ C, int ldc,
    int K, const float* __restrict__ bias, float* __restrict__ statsR)
{
    __shared__ unsigned short As[128 * 32];
    __shared__ unsigned short Bs[128 * 32];
    const int m0 = blockIdx.y * 128, n0 = blockIdx.x * 128;
    const int t = threadIdx.x;
    const int lane = t & 63, wave = t >> 6;
    const int wr = wave >> 1, wc = wave & 1;
    const int lrow = lane & 15, kq = (lane >> 4) * 8;
    const int r0 = t >> 2, c0 = (t & 3) * 8;

    f32x4 acc[4][4];
    #pragma unroll
    for (int i = 0; i < 4; ++i)
        #pragma unroll
        for (int j = 0; j < 4; ++j)
            acc[i][j] = (f32x4){0.f, 0.f, 0.f, 0.f};

    for (int k0 = 0; k0 < K; k0 += 32) {
        GLD_LDS(A + (long)(m0 + r0) * lda + k0 + c0,      &As[t * 8]);
        GLD_LDS(A + (long)(m0 + r0 + 64) * lda + k0 + c0, &As[(t + 256) * 8]);
        GLD_LDS(B + (long)(n0 + r0) * ldb + k0 + c0,      &Bs[t * 8]);
        GLD_LDS(B + (long)(n0 + r0 + 64) * ldb + k0 + c0, &Bs[(t + 256) * 8]);
        __syncthreads();
        short8 af[4], bf[4];
        #pragma unroll
        for (int i = 0; i < 4; ++i)
            af[i] = *(const short8*)&As[(wr * 64 + i * 16 + lrow) * 32 + kq];
        #pragma unroll
        for (int j = 0; j < 4; ++j)
            bf[j] = *(const short8*)&Bs[(wc * 64 + j * 16 + lrow) * 32 + kq];
        #pragma unroll
        for (int i = 0; i < 4; ++i)
            #pragma unroll
            for (int j = 0; j < 4; ++j)
                acc[i][j] = __builtin_amdgcn_mfma_f32_16x16x32_bf16(af[i], bf[j], acc[i][j], 0, 0, 0);
        __syncthreads();
    }

    const int cr = (lane >> 4) * 4;
    float* st = statsR + (blockIdx.y & 7) * 1152;
    #pragma unroll
    for (int j = 0; j < 4; ++j) {
        int col = n0 + wc * 64 + j * 16 + lrow;
        bool live = col < 576;
        float bv = live ? bias[col] : 0.f;
        float s1 = 0.f, s2 = 0.f;
        #pragma unroll
        for (int i = 0; i < 4; ++i) {
            long rowb = (long)(m0 + wr * 64 + i * 16 + cr) * ldc;
            #pragma unroll
            for (int r = 0; r < 4; ++r) {
                float v = acc[i][j][r] + bv;
                s1 += v; s2 += v * v;
                if (live) C[rowb + (long)r * ldc + col] = __float2bfloat16(v);
            }
        }
        s1 += __shfl_xor(s1, 16, 64); s1 += __shfl_xor(s1, 32, 64);
        s2 += __shfl_xor(s2, 16, 64); s2 += __shfl_xor(s2, 32, 64);
        if ((lane >> 4) == 0 && live) {
            atomicAdd(&st[col], s1);
            atomicAdd(&st[576 + col], s2);
        }
    }
}

// ---- fold BN stats into per-s scale/shift ----------------------------------
__global__ void bnfin_k(const float* __restrict__ statsR,
                        const float* __restrict__ gamma, const float* __restrict__ beta,
                        float* __restrict__ ab)
{
    int s = threadIdx.x;                             // 0..575
    float sum = 0.f, sq = 0.f;
    #pragma unroll
    for (int r = 0; r < 8; ++r) {
        sum += statsR[r * 1152 + s];
        sq  += statsR[r * 1152 + 576 + s];
    }
    float mu = sum * (1.f / 65536.f);
    float var = sq * (1.f / 65536.f) - mu * mu;
    float a = gamma[s] * rsqrtf(var + EPS);
    ab[s] = a;
    ab[576 + s] = beta[s] - mu * a;
}

// ---- epilogue: out = relu(x + 0.25 * (out3*a[s] + b[s])), float4 -----------
__global__ void final_k(const float4v* __restrict__ x4, const __hip_bfloat16* __restrict__ out3,
                        const float* __restrict__ ab, float4v* __restrict__ out4)
{
    int i = blockIdx.x * 256 + threadIdx.x;          // 0 .. 9,437,183
    int xx4 = i % 12; int t = i / 12;
    int y = t % 48; t /= 48;
    int c = t & 1023; int n = t >> 10;
    int xx = xx4 * 4;
    int ti = (y / 24) * 2 + (xx / 24);
    int b = ti * 16 + n;
    int s = (y % 24) * 24 + (xx % 24);
    const __hip_bfloat16* o3 = out3 + (((long)b << 10) + c) * 576 + s;
    float4v xv = x4[i];
    float4v o;
    #pragma unroll
    for (int e = 0; e < 4; ++e) {
        float v = __bfloat162float(o3[e]);
        float bn = v * ab[s + e] + ab[576 + s + e];
        float r = (e == 0 ? xv.x : e == 1 ? xv.y : e == 2 ? xv.z : xv.w) + 0.25f * bn;
        if (e == 0) o.x = fmaxf(r, 0.f);
        else if (e == 1) o.y = fmaxf(r, 0.f);
        else if (e == 2) o.z = fmaxf(r, 0.f);
        else o.w = fmaxf(r, 0.f);
    }
    out4[i] = o;
}

extern "C" void kernel_launch(void* const* d_in, const int* in_sizes, int n_in,
                              void* d_out, int out_size, void* d_ws, size_t ws_size,
                              hipStream_t stream)
{
    const float* x      = (const float*)d_in[0];
    const float* w_in1  = (const float*)d_in[1];
    const float* b_in1  = (const float*)d_in[2];
    const float* w_in2  = (const float*)d_in[3];
    const float* b_in2  = (const float*)d_in[4];
    const float* w_out1 = (const float*)d_in[5];
    const float* b_out1 = (const float*)d_in[6];
    const float* w_out2 = (const float*)d_in[7];
    const float* b_out2 = (const float*)d_in[8];
    const float* gamma  = (const float*)d_in[9];
    const float* beta   = (const float*)d_in[10];

    char* ws = (char*)d_ws;
    __hip_bfloat16* xv0    = (__hip_bfloat16*)(ws);                 // 75,497,472
    __hip_bfloat16* Hp     = (__hip_bfloat16*)(ws + 75497472L);     // 12,582,912
    __hip_bfloat16* out3   = (__hip_bfloat16*)(ws + 88080384L);     // 75,497,472
    __hip_bfloat16* xv1T   = (__hip_bfloat16*)(ws + 163577856L);    // 83,886,080
    float*          xmn    = (float*)(ws + 247463936L);             // 262,144
    float*          xm_raw = (float*)(ws + 247726080L);             // 262,144
    float*          invd   = (float*)(ws + 247988224L);             // 262,144
    float*          statsR = (float*)(ws + 248250368L);             // 36,864
    float*          ab     = (float*)(ws + 248287232L);             // 4,608
    __hip_bfloat16* w1p    = (__hip_bfloat16*)(ws + 248291840L);
    __hip_bfloat16* w1op   = (__hip_bfloat16*)(ws + 248439296L);
    __hip_bfloat16* w2p    = (__hip_bfloat16*)(ws + 248586752L);
    __hip_bfloat16* w2op   = (__hip_bfloat16*)(ws + 248709632L);
    float*          b1p    = (float*)(ws + 248832512L);
    float*          b1op   = (float*)(ws + 248833024L);
    __hip_bfloat16* out2   = xv0;                                   // reuse

    hipMemsetAsync(xm_raw, 0, 262144, stream);
    hipMemsetAsync(statsR, 0, 36864, stream);

    prep_k<<<288, 256, 0, stream>>>(w_in1, b_in1, w_in2, w_out1, b_out1, w_out2,
                                    w1p, w1op, w2p, w2op, b1p, b1op);

    extract_k<<<36864, 256, 0, stream>>>((const float4v*)x, xv0);

    // MLP1a: Hp = relu(xv0 @ w1p^T + b1p)   M=65536 N=96 K=576
    gemm_bf16<1,1><<<dim3(1, 512), 256, 0, stream>>>(
        (const unsigned short*)xv0, 576, (const unsigned short*)w1p, 576,
        Hp, 96, 96, 576, b1p);

    // MLP1b: xv1T = (Hp @ w2p^T + b_in2)^T per z, + row-mean atomics
    gemm_t<<<dim3(5, 512), 256, 0, stream>>>(
        (const unsigned short*)Hp, 96, (const unsigned short*)w2p, 96,
        xv1T, 96, b_in2, xm_raw);

    denom_k<<<128, 256, 0, stream>>>(xm_raw, b_in2, xmn, invd);

    // fused attention bmm -> out2 (reuses xv0)
    gemm_attn<<<2560, 256, 0, stream>>>(
        (const unsigned short*)xv1T, xmn, invd, out2);

    // MLP2a: Hp = relu(out2 @ w1op^T + b1op)
    gemm_bf16<1,1><<<dim3(1, 512), 256, 0, stream>>>(
        (const unsigned short*)out2, 576, (const unsigned short*)w1op, 576,
        Hp, 96, 96, 576, b1op);

    // MLP2b: out3 = Hp @ w2op^T + b_out2, + BN stat atomics
    gemm_bn<<<dim3(5, 512), 256, 0, stream>>>(
        (const unsigned short*)Hp, 96, (const unsigned short*)w2op, 96,
        out3, 576, 96, b_out2, statsR);

    bnfin_k<<<1, 576, 0, stream>>>(statsR, gamma, beta, ab);

    final_k<<<36864, 256, 0, stream>>>((const float4v*)x, out3, ab, (float4v*)d_out);
}